// Round 1
// baseline (1311.814 us; speedup 1.0000x reference)
//
#include <hip/hip_runtime.h>
#include <math.h>

#define N1 1024
#define NN2 (N1*N1)
#define LL 16384

// ---------------- elementwise ----------------
__global__ __launch_bounds__(256) void k_scale(const float* __restrict__ A,
                                               const float* __restrict__ logd,
                                               float* __restrict__ e) {
    int i = blockIdx.x * 256 + threadIdx.x;
    float d = expf(logd[0]);
    e[i] = 0.5f * d * A[i];
}

__global__ __launch_bounds__(256) void k_add(const float* __restrict__ a,
                                             const float* __restrict__ b,
                                             float* __restrict__ o) {
    int i = blockIdx.x * 256 + threadIdx.x;
    o[i] = a[i] + b[i];
}

// ---------------- 1024^3 SGEMM: C = alpha*(A@B) + beta*A ----------------
// BM=BN=64, BK=16, 256 threads, 4x4 per thread, grid (16,16)
__global__ __launch_bounds__(256) void k_mm(const float* __restrict__ A,
                                            const float* __restrict__ B,
                                            float* __restrict__ C,
                                            float alpha, float beta) {
    __shared__ float As[16][68];
    __shared__ float Bs[16][68];
    int t = threadIdx.x;
    int m0 = blockIdx.y * 64, n0 = blockIdx.x * 64;
    int tm = (t & 15) * 4;
    int tn = (t >> 4) * 4;
    int lm = t >> 2, lk = (t & 3) * 4;
    int lkb = t >> 4, ln = (t & 15) * 4;
    const float* Aptr = A + (size_t)(m0 + lm) * N1 + lk;
    const float* Bptr = B + (size_t)lkb * N1 + n0 + ln;

    float acc[4][4];
#pragma unroll
    for (int i = 0; i < 4; ++i)
#pragma unroll
        for (int j = 0; j < 4; ++j) acc[i][j] = 0.f;

    for (int k0 = 0; k0 < N1; k0 += 16) {
        float4 av = *(const float4*)(Aptr + k0);
        As[lk + 0][lm] = av.x;
        As[lk + 1][lm] = av.y;
        As[lk + 2][lm] = av.z;
        As[lk + 3][lm] = av.w;
        *(float4*)&Bs[lkb][ln] = *(const float4*)(Bptr + (size_t)k0 * N1);
        __syncthreads();
#pragma unroll
        for (int k = 0; k < 16; ++k) {
            float4 a = *(float4*)&As[k][tm];
            float4 b = *(float4*)&Bs[k][tn];
            acc[0][0] += a.x * b.x; acc[0][1] += a.x * b.y; acc[0][2] += a.x * b.z; acc[0][3] += a.x * b.w;
            acc[1][0] += a.y * b.x; acc[1][1] += a.y * b.y; acc[1][2] += a.y * b.z; acc[1][3] += a.y * b.w;
            acc[2][0] += a.z * b.x; acc[2][1] += a.z * b.y; acc[2][2] += a.z * b.z; acc[2][3] += a.z * b.w;
            acc[3][0] += a.w * b.x; acc[3][1] += a.w * b.y; acc[3][2] += a.w * b.z; acc[3][3] += a.w * b.w;
        }
        __syncthreads();
    }
#pragma unroll
    for (int i = 0; i < 4; ++i) {
        int row = m0 + tm + i;
        float4 addv = *(const float4*)&A[(size_t)row * N1 + n0 + tn];
        float4 o;
        o.x = alpha * acc[i][0] + beta * addv.x;
        o.y = alpha * acc[i][1] + beta * addv.y;
        o.z = alpha * acc[i][2] + beta * addv.z;
        o.w = alpha * acc[i][3] + beta * addv.w;
        *(float4*)&C[(size_t)row * N1 + n0 + tn] = o;
    }
}

// ---------------- transpose 1024x1024 ----------------
__global__ __launch_bounds__(256) void k_tr(const float* __restrict__ in,
                                            float* __restrict__ out) {
    __shared__ float tile[32][33];
    int tx = threadIdx.x & 31, ty = threadIdx.x >> 5;
    int x = blockIdx.x * 32 + tx, y0 = blockIdx.y * 32;
    for (int j = ty; j < 32; j += 8) tile[j][tx] = in[(size_t)(y0 + j) * N1 + x];
    __syncthreads();
    int x2 = blockIdx.y * 32 + tx, y2 = blockIdx.x * 32;
    for (int j = ty; j < 32; j += 8) out[(size_t)(y2 + j) * N1 + x2] = tile[tx][j];
}

// ---------------- chain doubling step: V[w+i] = (I + M) V[i], i in [0,w) ----------------
// grid = 16*w blocks, 256 threads; block -> (i = bx>>4, 64-row chunk = bx&15)
__global__ __launch_bounds__(256) void k_chain(const float* __restrict__ M,
                                               float* __restrict__ V, int w) {
    __shared__ float Vs[N1];
    int i = blockIdx.x >> 4, chunk = blockIdx.x & 15;
    int t = threadIdx.x;
    const float* Vi = V + (size_t)i * N1;
    *(float4*)&Vs[t * 4] = *(const float4*)&Vi[t * 4];
    __syncthreads();
    int wave = t >> 6, lane = t & 63;
    float* Vo = V + (size_t)(w + i) * N1;
    for (int rr = 0; rr < 16; ++rr) {
        int n = chunk * 64 + wave * 16 + rr;
        const float* Mr = M + (size_t)n * N1;
        float acc = 0.f;
#pragma unroll
        for (int jj = 0; jj < 4; ++jj) {
            int m = jj * 256 + lane * 4;
            float4 a = *(const float4*)&Mr[m];
            float4 v = *(const float4*)&Vs[m];
            acc += a.x * v.x + a.y * v.y + a.z * v.z + a.w * v.w;
        }
#pragma unroll
        for (int off = 32; off > 0; off >>= 1) acc += __shfl_down(acc, off, 64);
        if (lane == 0) Vo[n] = Vs[n] + acc;
    }
}

// ---------------- init: Q[0] = dB = d*(I + D/2) B ; P[0] = C ----------------
// grid 16 blocks x 256
__global__ __launch_bounds__(256) void k_init(const float* __restrict__ D1,
                                              const float* __restrict__ Bv,
                                              const float* __restrict__ Cv,
                                              const float* __restrict__ logd,
                                              float* __restrict__ Q,
                                              float* __restrict__ P) {
    int t = threadIdx.x;
    int gid = blockIdx.x * 256 + t;
    if (gid < N1) P[gid] = Cv[gid];
    __shared__ float Bs[N1];
    *(float4*)&Bs[t * 4] = *(const float4*)&Bv[t * 4];
    __syncthreads();
    float d = expf(logd[0]);
    int wave = t >> 6, lane = t & 63;
    for (int rr = 0; rr < 16; ++rr) {
        int n = blockIdx.x * 64 + wave * 16 + rr;
        const float* Mr = D1 + (size_t)n * N1;
        float acc = 0.f;
#pragma unroll
        for (int jj = 0; jj < 4; ++jj) {
            int m = jj * 256 + lane * 4;
            float4 a = *(const float4*)&Mr[m];
            float4 v = *(const float4*)&Bs[m];
            acc += a.x * v.x + a.y * v.y + a.z * v.z + a.w * v.w;
        }
#pragma unroll
        for (int off = 32; off > 0; off >>= 1) acc += __shfl_down(acc, off, 64);
        if (lane == 0) Q[n] = d * (Bs[n] + 0.5f * acc);
    }
}

// ---------------- K[a*128+b] = dot(P[a], Q[b]) ----------------
// grid 4096 x 256 (one wave per K entry)
__global__ __launch_bounds__(256) void k_kdot(const float* __restrict__ P,
                                              const float* __restrict__ Q,
                                              float* __restrict__ K) {
    int t = threadIdx.x;
    int wid = blockIdx.x * 4 + (t >> 6), lane = t & 63;
    int a = wid >> 7, b = wid & 127;
    const float* Pr = P + (size_t)a * N1;
    const float* Qr = Q + (size_t)b * N1;
    float acc = 0.f;
#pragma unroll
    for (int jj = 0; jj < 4; ++jj) {
        int m = jj * 256 + lane * 4;
        float4 p = *(const float4*)&Pr[m];
        float4 q = *(const float4*)&Qr[m];
        acc += p.x * q.x + p.y * q.y + p.z * q.z + p.w * q.w;
    }
#pragma unroll
    for (int off = 32; off > 0; off >>= 1) acc += __shfl_down(acc, off, 64);
    if (lane == 0) K[wid] = acc;
}

// ---------------- causal conv: y[t] = Dskip*x[t] + sum_{j<=t} K[t-j] x[j] ----------------
// grid 64 blocks x 256 threads, 256-wide tiles
__global__ __launch_bounds__(256) void k_conv(const float* __restrict__ X,
                                              const float* __restrict__ K,
                                              const float* __restrict__ Dp,
                                              float* __restrict__ Y) {
    int b = blockIdx.x, tt = threadIdx.x;
    int tgl = b * 256 + tt;
    __shared__ float xs[256];
    __shared__ float ks[512];
    float acc = 0.f;
    for (int jt = 0; jt <= b; ++jt) {
        __syncthreads();
        xs[tt] = X[jt * 256 + tt];
        int m0 = (b - jt) * 256 - 255;
        for (int ii = tt; ii < 512; ii += 256) {
            int m = m0 + ii;
            ks[ii] = (m >= 0 && m < LL) ? K[m] : 0.f;
        }
        __syncthreads();
#pragma unroll 8
        for (int jj = 0; jj < 256; ++jj) acc += ks[tt - jj + 255] * xs[jj];
    }
    Y[tgl] = Dp[0] * X[tgl] + acc;
}

extern "C" void kernel_launch(void* const* d_in, const int* in_sizes, int n_in,
                              void* d_out, int out_size, void* d_ws, size_t ws_size,
                              hipStream_t stream) {
    const float* X    = (const float*)d_in[0];
    const float* A    = (const float*)d_in[1];
    const float* Bv   = (const float*)d_in[2];
    const float* Cv   = (const float*)d_in[3];
    const float* Dp   = (const float*)d_in[4];
    const float* logd = (const float*)d_in[5];
    float* ws = (float*)d_ws;

    float* S0 = ws;                 // e, later squaring ping-pong
    float* S1 = ws + (size_t)NN2;   // e2, later transpose buffer
    float* S2 = ws + 2*(size_t)NN2; // w = e2 + e4
    float* S3 = ws + 3*(size_t)NN2; // t1 = e + e2
    float* S4 = ws + 4*(size_t)NN2; // D1, squaring ping-pong
    float* Q  = ws + 5*(size_t)NN2;         // 128 x 1024
    float* P  = Q + 128*(size_t)N1;         // 128 x 1024
    float* Kc = P + 128*(size_t)N1;         // 16384
    float* Y  = (float*)d_out;

    dim3 mmg(16, 16);
    // e = (d/2) A
    k_scale<<<4096, 256, 0, stream>>>(A, logd, S0);
    // e2 = e*e
    k_mm<<<mmg, 256, 0, stream>>>(S0, S0, S1, 1.f, 0.f);
    // w = e2*e2 + e2 = e^2 + e^4
    k_mm<<<mmg, 256, 0, stream>>>(S1, S1, S2, 1.f, 1.f);
    // t1 = e + e2 = e(I+e)
    k_add<<<4096, 256, 0, stream>>>(S0, S1, S3);
    // D1 = 2*(t1*w + t1) = 2 e (I+e)(I+e^2+e^4)  ~= dA - I
    k_mm<<<mmg, 256, 0, stream>>>(S3, S2, S4, 2.f, 2.f);
    // Q[0] = dB, P[0] = C
    k_init<<<16, 256, 0, stream>>>(S4, Bv, Cv, logd, Q, P);

    // Q doubling with D_{2^k}; squarings D -> D^2 + 2D
    float* cur = S4;
    float* nxt = S0;
    for (int k = 0; k < 7; ++k) {
        k_chain<<<16 << k, 256, 0, stream>>>(cur, Q, 1 << k);
        k_mm<<<mmg, 256, 0, stream>>>(cur, cur, nxt, 1.f, 2.f);
        float* tsw = cur; cur = nxt; nxt = tsw;
    }
    // cur = D128. P doubling with transposes of D_{128*2^k}
    for (int k = 0; k < 7; ++k) {
        k_tr<<<dim3(32, 32), 256, 0, stream>>>(cur, S1);
        k_chain<<<16 << k, 256, 0, stream>>>(S1, P, 1 << k);
        if (k < 6) {
            k_mm<<<mmg, 256, 0, stream>>>(cur, cur, nxt, 1.f, 2.f);
            float* tsw = cur; cur = nxt; nxt = tsw;
        }
    }
    // K[a*128+b] = P[a] . Q[b]
    k_kdot<<<4096, 256, 0, stream>>>(P, Q, Kc);
    // y = Dskip*x + causal conv(K, x)
    k_conv<<<64, 256, 0, stream>>>(X, Kc, Dp, Y);
}

// Round 2
// 1181.626 us; speedup vs baseline: 1.1102x; 1.1102x over previous
//
#include <hip/hip_runtime.h>
#include <math.h>

#define N1 1024
#define NN2 (N1*N1)
#define LL 16384

// ---------------- elementwise ----------------
__global__ __launch_bounds__(256) void k_scale(const float* __restrict__ A,
                                               const float* __restrict__ logd,
                                               float* __restrict__ e) {
    int i = blockIdx.x * 256 + threadIdx.x;
    float d = expf(logd[0]);
    e[i] = 0.5f * d * A[i];
}

__global__ __launch_bounds__(256) void k_add(const float* __restrict__ a,
                                             const float* __restrict__ b,
                                             float* __restrict__ o) {
    int i = blockIdx.x * 256 + threadIdx.x;
    o[i] = a[i] + b[i];
}

// ---------------- 1024^3 SGEMM: C = alpha*(A@B) + beta*A ----------------
// BM=BN=64, BK=32, 256 threads, 4x4/thread, grid (16,16), reg-prefetch pipeline
__global__ __launch_bounds__(256) void k_mm(const float* __restrict__ A,
                                            const float* __restrict__ B,
                                            float* __restrict__ C,
                                            float alpha, float beta) {
    __shared__ float As[32][68];
    __shared__ float Bs[32][68];
    int t = threadIdx.x;
    int m0 = blockIdx.y * 64, n0 = blockIdx.x * 64;
    int tm = (t & 15) * 4, tn = (t >> 4) * 4;
    int lmA = t >> 2, lkA = (t & 3) * 8;     // A stage: 64 rows x 32 k
    int kbB = t >> 3, nbB = (t & 7) * 8;     // B stage: 32 k x 64 n
    const float* Ap = A + (size_t)(m0 + lmA) * N1 + lkA;
    const float* Bp = B + (size_t)kbB * N1 + n0 + nbB;

    float4 pa0 = *(const float4*)(Ap);
    float4 pa1 = *(const float4*)(Ap + 4);
    float4 pb0 = *(const float4*)(Bp);
    float4 pb1 = *(const float4*)(Bp + 4);

    float acc[4][4];
#pragma unroll
    for (int i = 0; i < 4; ++i)
#pragma unroll
        for (int j = 0; j < 4; ++j) acc[i][j] = 0.f;

    for (int k0 = 0; k0 < N1; k0 += 32) {
        As[lkA + 0][lmA] = pa0.x; As[lkA + 1][lmA] = pa0.y;
        As[lkA + 2][lmA] = pa0.z; As[lkA + 3][lmA] = pa0.w;
        As[lkA + 4][lmA] = pa1.x; As[lkA + 5][lmA] = pa1.y;
        As[lkA + 6][lmA] = pa1.z; As[lkA + 7][lmA] = pa1.w;
        *(float4*)&Bs[kbB][nbB]     = pb0;
        *(float4*)&Bs[kbB][nbB + 4] = pb1;
        __syncthreads();
        if (k0 + 32 < N1) {
            pa0 = *(const float4*)(Ap + k0 + 32);
            pa1 = *(const float4*)(Ap + k0 + 36);
            pb0 = *(const float4*)(Bp + (size_t)(k0 + 32) * N1);
            pb1 = *(const float4*)(Bp + (size_t)(k0 + 32) * N1 + 4);
        }
#pragma unroll
        for (int k = 0; k < 32; ++k) {
            float4 a = *(float4*)&As[k][tm];
            float4 b = *(float4*)&Bs[k][tn];
            acc[0][0] += a.x * b.x; acc[0][1] += a.x * b.y; acc[0][2] += a.x * b.z; acc[0][3] += a.x * b.w;
            acc[1][0] += a.y * b.x; acc[1][1] += a.y * b.y; acc[1][2] += a.y * b.z; acc[1][3] += a.y * b.w;
            acc[2][0] += a.z * b.x; acc[2][1] += a.z * b.y; acc[2][2] += a.z * b.z; acc[2][3] += a.z * b.w;
            acc[3][0] += a.w * b.x; acc[3][1] += a.w * b.y; acc[3][2] += a.w * b.z; acc[3][3] += a.w * b.w;
        }
        __syncthreads();
    }
#pragma unroll
    for (int i = 0; i < 4; ++i) {
        int row = m0 + tm + i;
        float4 addv = *(const float4*)&A[(size_t)row * N1 + n0 + tn];
        float4 o;
        o.x = alpha * acc[i][0] + beta * addv.x;
        o.y = alpha * acc[i][1] + beta * addv.y;
        o.z = alpha * acc[i][2] + beta * addv.z;
        o.w = alpha * acc[i][3] + beta * addv.w;
        *(float4*)&C[(size_t)row * N1 + n0 + tn] = o;
    }
}

// ---------------- Q chain: V[w+i] = (I + M) V[i] (matvec, M rows) ----------------
__global__ __launch_bounds__(256) void k_chain(const float* __restrict__ M,
                                               float* __restrict__ V, int w) {
    __shared__ float Vs[N1];
    int i = blockIdx.x >> 4, chunk = blockIdx.x & 15;
    int t = threadIdx.x;
    const float* Vi = V + (size_t)i * N1;
    *(float4*)&Vs[t * 4] = *(const float4*)&Vi[t * 4];
    __syncthreads();
    int wave = t >> 6, lane = t & 63;
    float* Vo = V + (size_t)(w + i) * N1;
    for (int rr = 0; rr < 16; ++rr) {
        int n = chunk * 64 + wave * 16 + rr;
        const float* Mr = M + (size_t)n * N1;
        float acc = 0.f;
#pragma unroll
        for (int jj = 0; jj < 4; ++jj) {
            int m = jj * 256 + lane * 4;
            float4 a = *(const float4*)&Mr[m];
            float4 v = *(const float4*)&Vs[m];
            acc += a.x * v.x + a.y * v.y + a.z * v.z + a.w * v.w;
        }
#pragma unroll
        for (int off = 32; off > 0; off >>= 1) acc += __shfl_down(acc, off, 64);
        if (lane == 0) Vo[n] = Vs[n] + acc;
    }
}

// ---------------- P chain: P[w+i] = P[i] (I + M) (row-vec x matrix, no transpose) ----
// grid dim3(4, w), 256 threads
__global__ __launch_bounds__(256) void k_chainP(const float* __restrict__ M,
                                                float* __restrict__ P, int w) {
    __shared__ float Ps[N1];
    int i = blockIdx.y, t = threadIdx.x;
    int n = blockIdx.x * 256 + t;
    const float* Pi = P + (size_t)i * N1;
    *(float4*)&Ps[t * 4] = *(const float4*)&Pi[t * 4];
    __syncthreads();
    float acc = Ps[n & (N1 - 1)];
#pragma unroll 8
    for (int m = 0; m < N1; ++m)
        acc += Ps[m] * M[(size_t)m * N1 + n];
    P[(size_t)(w + i) * N1 + n] = acc;
}

// ---------------- init: Q[0] = dB = d*(I + D/2) B ; P[0] = C ----------------
__global__ __launch_bounds__(256) void k_init(const float* __restrict__ D1,
                                              const float* __restrict__ Bv,
                                              const float* __restrict__ Cv,
                                              const float* __restrict__ logd,
                                              float* __restrict__ Q,
                                              float* __restrict__ P) {
    int t = threadIdx.x;
    int gid = blockIdx.x * 256 + t;
    if (gid < N1) P[gid] = Cv[gid];
    __shared__ float Bs[N1];
    *(float4*)&Bs[t * 4] = *(const float4*)&Bv[t * 4];
    __syncthreads();
    float d = expf(logd[0]);
    int wave = t >> 6, lane = t & 63;
    for (int rr = 0; rr < 16; ++rr) {
        int n = blockIdx.x * 64 + wave * 16 + rr;
        const float* Mr = D1 + (size_t)n * N1;
        float acc = 0.f;
#pragma unroll
        for (int jj = 0; jj < 4; ++jj) {
            int m = jj * 256 + lane * 4;
            float4 a = *(const float4*)&Mr[m];
            float4 v = *(const float4*)&Bs[m];
            acc += a.x * v.x + a.y * v.y + a.z * v.z + a.w * v.w;
        }
#pragma unroll
        for (int off = 32; off > 0; off >>= 1) acc += __shfl_down(acc, off, 64);
        if (lane == 0) Q[n] = d * (Bs[n] + 0.5f * acc);
    }
}

// ---------------- K[a*128+b] = dot(P[a], Q[b]) ----------------
__global__ __launch_bounds__(256) void k_kdot(const float* __restrict__ P,
                                              const float* __restrict__ Q,
                                              float* __restrict__ K) {
    int t = threadIdx.x;
    int wid = blockIdx.x * 4 + (t >> 6), lane = t & 63;
    int a = wid >> 7, b = wid & 127;
    const float* Pr = P + (size_t)a * N1;
    const float* Qr = Q + (size_t)b * N1;
    float acc = 0.f;
#pragma unroll
    for (int jj = 0; jj < 4; ++jj) {
        int m = jj * 256 + lane * 4;
        float4 p = *(const float4*)&Pr[m];
        float4 q = *(const float4*)&Qr[m];
        acc += p.x * q.x + p.y * q.y + p.z * q.z + p.w * q.w;
    }
#pragma unroll
    for (int off = 32; off > 0; off >>= 1) acc += __shfl_down(acc, off, 64);
    if (lane == 0) K[wid] = acc;
}

// ---------------- conv phase 1: partial sums per (output-1024-tile, input-256-tile) ---
// grid 544: block -> (o, jt), o in [0,16), jt in [0, 4o+4)
// part[(o*64+jt)*1024 + c] = sum_{j in tile jt} K[t-j] x[j],  t = o*1024 + c
__global__ __launch_bounds__(256) void k_conv1(const float* __restrict__ X,
                                               const float* __restrict__ K,
                                               float* __restrict__ part) {
    __shared__ __align__(16) float ks[1280];
    __shared__ __align__(16) float xs[256];
    int bx = blockIdx.x, tt = threadIdx.x;
    int o = 0;
    while (bx >= 2 * (o + 1) * (o + 1) + 2 * (o + 1)) ++o;
    int jt = bx - (2 * o * o + 2 * o);
    int T0 = o * 1024, J0 = jt * 256;
    int mb = T0 - J0 - 255;
    for (int ii = tt; ii < 1280; ii += 256) {
        int m = mb + ii;
        ks[ii] = (m >= 0 && m < LL) ? K[m] : 0.f;
    }
    xs[tt] = X[J0 + tt];
    __syncthreads();

    float acc0 = 0.f, acc1 = 0.f, acc2 = 0.f, acc3 = 0.f;
    int base0 = 4 * tt + 252;
#pragma unroll 4
    for (int jj = 0; jj < 256; jj += 4) {
        float4 xv  = *(const float4*)&xs[jj];
        float4 kv0 = *(const float4*)&ks[base0 - jj];
        float4 kv1 = *(const float4*)&ks[base0 - jj + 4];
        float kk0 = kv0.x, kk1 = kv0.y, kk2 = kv0.z, kk3 = kv0.w;
        float kk4 = kv1.x, kk5 = kv1.y, kk6 = kv1.z, kk7 = kv1.w;
        // acc[r] += kk[3 + r - s] * xv[s]
        acc0 += kk3 * xv.x + kk2 * xv.y + kk1 * xv.z + kk0 * xv.w;
        acc1 += kk4 * xv.x + kk3 * xv.y + kk2 * xv.z + kk1 * xv.w;
        acc2 += kk5 * xv.x + kk4 * xv.y + kk3 * xv.z + kk2 * xv.w;
        acc3 += kk6 * xv.x + kk5 * xv.y + kk4 * xv.z + kk3 * xv.w;
    }
    float4 out = {acc0, acc1, acc2, acc3};
    *(float4*)&part[((size_t)(o * 64 + jt)) * 1024 + 4 * tt] = out;
}

// ---------------- conv phase 2: reduce partials + skip ----------------
__global__ __launch_bounds__(256) void k_conv2(const float* __restrict__ X,
                                               const float* __restrict__ part,
                                               const float* __restrict__ Dp,
                                               float* __restrict__ Y) {
    int o = blockIdx.x, tt = threadIdx.x;
    int c = 4 * tt;
    float s0 = 0.f, s1 = 0.f, s2 = 0.f, s3 = 0.f;
    int cnt = 4 * o + 4;
    for (int jt = 0; jt < cnt; ++jt) {
        float4 p = *(const float4*)&part[((size_t)(o * 64 + jt)) * 1024 + c];
        s0 += p.x; s1 += p.y; s2 += p.z; s3 += p.w;
    }
    float dsk = Dp[0];
    int t = o * 1024 + c;
    float4 xv = *(const float4*)&X[t];
    float4 out;
    out.x = dsk * xv.x + s0;
    out.y = dsk * xv.y + s1;
    out.z = dsk * xv.z + s2;
    out.w = dsk * xv.w + s3;
    *(float4*)&Y[t] = out;
}

extern "C" void kernel_launch(void* const* d_in, const int* in_sizes, int n_in,
                              void* d_out, int out_size, void* d_ws, size_t ws_size,
                              hipStream_t stream) {
    const float* X    = (const float*)d_in[0];
    const float* A    = (const float*)d_in[1];
    const float* Bv   = (const float*)d_in[2];
    const float* Cv   = (const float*)d_in[3];
    const float* Dp   = (const float*)d_in[4];
    const float* logd = (const float*)d_in[5];
    float* ws = (float*)d_ws;

    float* S0 = ws;                 // e, squaring ping-pong
    float* S1 = ws + (size_t)NN2;   // e2, later conv partials
    float* S2 = ws + 2*(size_t)NN2; // e^2+e^4
    float* S3 = ws + 3*(size_t)NN2; // e+e^2
    float* S4 = ws + 4*(size_t)NN2; // D1, squaring ping-pong
    float* Q  = ws + 5*(size_t)NN2;         // 128 x 1024
    float* P  = Q + 128*(size_t)N1;         // 128 x 1024
    float* Kc = P + 128*(size_t)N1;         // 16384
    float* Y  = (float*)d_out;

    dim3 mmg(16, 16);
    k_scale<<<4096, 256, 0, stream>>>(A, logd, S0);              // e = (d/2)A
    k_mm<<<mmg, 256, 0, stream>>>(S0, S0, S1, 1.f, 0.f);         // e^2
    k_mm<<<mmg, 256, 0, stream>>>(S1, S1, S2, 1.f, 1.f);         // e^2 + e^4
    k_add<<<4096, 256, 0, stream>>>(S0, S1, S3);                 // e + e^2
    k_mm<<<mmg, 256, 0, stream>>>(S3, S2, S4, 2.f, 2.f);         // D1 = 2e(I+e)(I+e^2+e^4)
    k_init<<<16, 256, 0, stream>>>(S4, Bv, Cv, logd, Q, P);

    // Q doubling with D_{2^k}; squaring D -> D^2 + 2D
    float* cur = S4;
    float* nxt = S0;
    for (int k = 0; k < 7; ++k) {
        k_chain<<<16 << k, 256, 0, stream>>>(cur, Q, 1 << k);
        k_mm<<<mmg, 256, 0, stream>>>(cur, cur, nxt, 1.f, 2.f);
        float* tsw = cur; cur = nxt; nxt = tsw;
    }
    // cur = D_128: P doubling (row form, no transpose)
    for (int k = 0; k < 7; ++k) {
        k_chainP<<<dim3(4, 1 << k), 256, 0, stream>>>(cur, P, 1 << k);
        if (k < 6) {
            k_mm<<<mmg, 256, 0, stream>>>(cur, cur, nxt, 1.f, 2.f);
            float* tsw = cur; cur = nxt; nxt = tsw;
        }
    }
    k_kdot<<<4096, 256, 0, stream>>>(P, Q, Kc);
    k_conv1<<<544, 256, 0, stream>>>(X, Kc, S1);
    k_conv2<<<16, 256, 0, stream>>>(X, S1, Dp, Y);
}

// Round 3
// 887.921 us; speedup vs baseline: 1.4774x; 1.3308x over previous
//
#include <hip/hip_runtime.h>
#include <math.h>

#define N1 1024
#define NN2 (N1*N1)
#define LL 16384

// ---------------- elementwise ----------------
__global__ __launch_bounds__(256) void k_scale(const float* __restrict__ A,
                                               const float* __restrict__ logd,
                                               float* __restrict__ e) {
    int i = blockIdx.x * 256 + threadIdx.x;
    float d = expf(logd[0]);
    e[i] = 0.5f * d * A[i];
}

__global__ __launch_bounds__(256) void k_add(const float* __restrict__ a,
                                             const float* __restrict__ b,
                                             float* __restrict__ o) {
    int i = blockIdx.x * 256 + threadIdx.x;
    o[i] = a[i] + b[i];
}

// ---------------- SGEMM partial: part[z] = A[:, zK:zK+512] @ B[zK:zK+512, :] ------
// BM=BN=64, BK=32, 256 threads, 4x4/thread, grid (16,16,2)
__global__ __launch_bounds__(256) void k_mmk(const float* __restrict__ A,
                                             const float* __restrict__ B,
                                             float* __restrict__ part) {
    __shared__ float As[32][68];
    __shared__ float Bs[32][68];
    int t = threadIdx.x;
    int m0 = blockIdx.y * 64, n0 = blockIdx.x * 64;
    int kz = blockIdx.z * 512;
    int tm = (t & 15) * 4, tn = (t >> 4) * 4;
    int lmA = t >> 2, lkA = (t & 3) * 8;     // A stage: 64 rows x 32 k
    int kbB = t >> 3, nbB = (t & 7) * 8;     // B stage: 32 k x 64 n
    const float* Ap = A + (size_t)(m0 + lmA) * N1 + kz + lkA;
    const float* Bp = B + (size_t)(kz + kbB) * N1 + n0 + nbB;

    float4 pa0 = *(const float4*)(Ap);
    float4 pa1 = *(const float4*)(Ap + 4);
    float4 pb0 = *(const float4*)(Bp);
    float4 pb1 = *(const float4*)(Bp + 4);

    float acc[4][4];
#pragma unroll
    for (int i = 0; i < 4; ++i)
#pragma unroll
        for (int j = 0; j < 4; ++j) acc[i][j] = 0.f;

    for (int k0 = 0; k0 < 512; k0 += 32) {
        As[lkA + 0][lmA] = pa0.x; As[lkA + 1][lmA] = pa0.y;
        As[lkA + 2][lmA] = pa0.z; As[lkA + 3][lmA] = pa0.w;
        As[lkA + 4][lmA] = pa1.x; As[lkA + 5][lmA] = pa1.y;
        As[lkA + 6][lmA] = pa1.z; As[lkA + 7][lmA] = pa1.w;
        *(float4*)&Bs[kbB][nbB]     = pb0;
        *(float4*)&Bs[kbB][nbB + 4] = pb1;
        __syncthreads();
        if (k0 + 32 < 512) {
            pa0 = *(const float4*)(Ap + k0 + 32);
            pa1 = *(const float4*)(Ap + k0 + 36);
            pb0 = *(const float4*)(Bp + (size_t)(k0 + 32) * N1);
            pb1 = *(const float4*)(Bp + (size_t)(k0 + 32) * N1 + 4);
        }
#pragma unroll
        for (int k = 0; k < 32; ++k) {
            float4 a = *(float4*)&As[k][tm];
            float4 b = *(float4*)&Bs[k][tn];
            acc[0][0] += a.x * b.x; acc[0][1] += a.x * b.y; acc[0][2] += a.x * b.z; acc[0][3] += a.x * b.w;
            acc[1][0] += a.y * b.x; acc[1][1] += a.y * b.y; acc[1][2] += a.y * b.z; acc[1][3] += a.y * b.w;
            acc[2][0] += a.z * b.x; acc[2][1] += a.z * b.y; acc[2][2] += a.z * b.z; acc[2][3] += a.z * b.w;
            acc[3][0] += a.w * b.x; acc[3][1] += a.w * b.y; acc[3][2] += a.w * b.z; acc[3][3] += a.w * b.w;
        }
        __syncthreads();
    }
    float* Po = part + (size_t)blockIdx.z * NN2;
#pragma unroll
    for (int i = 0; i < 4; ++i) {
        float4 o = {acc[i][0], acc[i][1], acc[i][2], acc[i][3]};
        *(float4*)&Po[(size_t)(m0 + tm + i) * N1 + n0 + tn] = o;
    }
}

// C = alpha*(part0+part1) + beta*Aadd   (grid 1024 x 256, float4)
__global__ __launch_bounds__(256) void k_mmred(const float* __restrict__ part,
                                               const float* __restrict__ Aadd,
                                               float* __restrict__ C,
                                               float alpha, float beta) {
    int i = (blockIdx.x * 256 + threadIdx.x) * 4;
    float4 p0 = *(const float4*)&part[i];
    float4 p1 = *(const float4*)&part[NN2 + i];
    float4 av = *(const float4*)&Aadd[i];
    float4 o;
    o.x = alpha * (p0.x + p1.x) + beta * av.x;
    o.y = alpha * (p0.y + p1.y) + beta * av.y;
    o.z = alpha * (p0.z + p1.z) + beta * av.z;
    o.w = alpha * (p0.w + p1.w) + beta * av.w;
    *(float4*)&C[i] = o;
}

// ---------------- Q chain partial: part[i][kc][n] = M[n, m0:m0+mlen] . V[i][m0:] ----
// grid dim3(16, kc, w), 256 threads
__global__ __launch_bounds__(256) void k_chainQ1(const float* __restrict__ M,
                                                 const float* __restrict__ V,
                                                 float* __restrict__ part,
                                                 int kc, int mlen) {
    __shared__ float Vs[256];
    int i = blockIdx.z, t = threadIdx.x;
    int n0 = blockIdx.x * 64, m0 = blockIdx.y * mlen;
    const float* Vi = V + (size_t)i * N1 + m0;
    if (t * 4 < mlen) *(float4*)&Vs[t * 4] = *(const float4*)&Vi[t * 4];
    __syncthreads();
    int wave = t >> 6, lane = t & 63;
    for (int rr = 0; rr < 16; ++rr) {
        int n = n0 + wave * 16 + rr;
        const float* Mr = M + (size_t)n * N1 + m0;
        float acc = 0.f;
        for (int m = lane * 4; m < mlen; m += 256) {
            float4 a = *(const float4*)&Mr[m];
            float4 v = *(const float4*)&Vs[m];
            acc += a.x * v.x + a.y * v.y + a.z * v.z + a.w * v.w;
        }
#pragma unroll
        for (int off = 32; off > 0; off >>= 1) acc += __shfl_down(acc, off, 64);
        if (lane == 0) part[((size_t)i * kc + blockIdx.y) * N1 + n] = acc;
    }
}

// ---------------- P chain partial: part[i][kc][n] = P[i][m0:] . M[m0:, n] ----------
// grid dim3(16, kc, w), 256 threads
__global__ __launch_bounds__(256) void k_chainP1(const float* __restrict__ M,
                                                 const float* __restrict__ P,
                                                 float* __restrict__ part,
                                                 int kc, int mlen) {
    __shared__ float Ps[256];
    __shared__ float red[4][64];
    int i = blockIdx.z, t = threadIdx.x;
    int n0 = blockIdx.x * 64, m0 = blockIdx.y * mlen;
    const float* Pi = P + (size_t)i * N1 + m0;
    if (t * 4 < mlen) *(float4*)&Ps[t * 4] = *(const float4*)&Pi[t * 4];
    __syncthreads();
    int wave = t >> 6, lane = t & 63;
    int n = n0 + lane;
    int msub = mlen >> 2;
    int mb = wave * msub;
    float acc = 0.f;
#pragma unroll 8
    for (int m = 0; m < msub; ++m)
        acc += Ps[mb + m] * M[(size_t)(m0 + mb + m) * N1 + n];
    red[wave][lane] = acc;
    __syncthreads();
    if (t < 64) {
        float s = red[0][t] + red[1][t] + red[2][t] + red[3][t];
        part[((size_t)i * kc + blockIdx.y) * N1 + n0 + t] = s;
    }
}

// ---------------- chain reduce: V[w+i][n] = V[i][n] + sum_c part[i][c][n] ----------
// grid dim3(4, w), 256 threads
__global__ __launch_bounds__(256) void k_chainR(float* __restrict__ V,
                                                const float* __restrict__ part,
                                                int w, int kc) {
    int i = blockIdx.y, t = threadIdx.x;
    int n = blockIdx.x * 256 + t;
    const float* pp = part + (size_t)i * kc * N1 + n;
    float s = 0.f;
    for (int c = 0; c < kc; ++c) s += pp[(size_t)c * N1];
    V[(size_t)(w + i) * N1 + n] = V[(size_t)i * N1 + n] + s;
}

// ---------------- init reduce: Q[0] = d*(B + 0.5*D1@B); P[0] = C ----------------
__global__ __launch_bounds__(256) void k_initR(const float* __restrict__ Bv,
                                               const float* __restrict__ Cv,
                                               const float* __restrict__ logd,
                                               const float* __restrict__ part,
                                               float* __restrict__ Q,
                                               float* __restrict__ P) {
    int n = blockIdx.x * 256 + threadIdx.x;
    float s = 0.f;
    for (int c = 0; c < 16; ++c) s += part[(size_t)c * N1 + n];
    float d = expf(logd[0]);
    Q[n] = d * (Bv[n] + 0.5f * s);
    P[n] = Cv[n];
}

// ---------------- K[a*128+b] = dot(P[a], Q[b]) ----------------
__global__ __launch_bounds__(256) void k_kdot(const float* __restrict__ P,
                                              const float* __restrict__ Q,
                                              float* __restrict__ K) {
    int t = threadIdx.x;
    int wid = blockIdx.x * 4 + (t >> 6), lane = t & 63;
    int a = wid >> 7, b = wid & 127;
    const float* Pr = P + (size_t)a * N1;
    const float* Qr = Q + (size_t)b * N1;
    float acc = 0.f;
#pragma unroll
    for (int jj = 0; jj < 4; ++jj) {
        int m = jj * 256 + lane * 4;
        float4 p = *(const float4*)&Pr[m];
        float4 q = *(const float4*)&Qr[m];
        acc += p.x * q.x + p.y * q.y + p.z * q.z + p.w * q.w;
    }
#pragma unroll
    for (int off = 32; off > 0; off >>= 1) acc += __shfl_down(acc, off, 64);
    if (lane == 0) K[wid] = acc;
}

// ---------------- conv phase 1 ----------------
__global__ __launch_bounds__(256) void k_conv1(const float* __restrict__ X,
                                               const float* __restrict__ K,
                                               float* __restrict__ part) {
    __shared__ __align__(16) float ks[1280];
    __shared__ __align__(16) float xs[256];
    int bx = blockIdx.x, tt = threadIdx.x;
    int o = 0;
    while (bx >= 2 * (o + 1) * (o + 1) + 2 * (o + 1)) ++o;
    int jt = bx - (2 * o * o + 2 * o);
    int T0 = o * 1024, J0 = jt * 256;
    int mb = T0 - J0 - 255;
    for (int ii = tt; ii < 1280; ii += 256) {
        int m = mb + ii;
        ks[ii] = (m >= 0 && m < LL) ? K[m] : 0.f;
    }
    xs[tt] = X[J0 + tt];
    __syncthreads();

    float acc0 = 0.f, acc1 = 0.f, acc2 = 0.f, acc3 = 0.f;
    int base0 = 4 * tt + 252;
#pragma unroll 4
    for (int jj = 0; jj < 256; jj += 4) {
        float4 xv  = *(const float4*)&xs[jj];
        float4 kv0 = *(const float4*)&ks[base0 - jj];
        float4 kv1 = *(const float4*)&ks[base0 - jj + 4];
        float kk0 = kv0.x, kk1 = kv0.y, kk2 = kv0.z, kk3 = kv0.w;
        float kk4 = kv1.x, kk5 = kv1.y, kk6 = kv1.z;
        acc0 += kk3 * xv.x + kk2 * xv.y + kk1 * xv.z + kk0 * xv.w;
        acc1 += kk4 * xv.x + kk3 * xv.y + kk2 * xv.z + kk1 * xv.w;
        acc2 += kk5 * xv.x + kk4 * xv.y + kk3 * xv.z + kk2 * xv.w;
        acc3 += kk6 * xv.x + kk5 * xv.y + kk4 * xv.z + kk3 * xv.w;
    }
    float4 out = {acc0, acc1, acc2, acc3};
    *(float4*)&part[((size_t)(o * 64 + jt)) * 1024 + 4 * tt] = out;
}

// ---------------- conv phase 2 ----------------
__global__ __launch_bounds__(256) void k_conv2(const float* __restrict__ X,
                                               const float* __restrict__ part,
                                               const float* __restrict__ Dp,
                                               float* __restrict__ Y) {
    int o = blockIdx.x, tt = threadIdx.x;
    int c = 4 * tt;
    float s0 = 0.f, s1 = 0.f, s2 = 0.f, s3 = 0.f;
    int cnt = 4 * o + 4;
    for (int jt = 0; jt < cnt; ++jt) {
        float4 p = *(const float4*)&part[((size_t)(o * 64 + jt)) * 1024 + c];
        s0 += p.x; s1 += p.y; s2 += p.z; s3 += p.w;
    }
    float dsk = Dp[0];
    int t = o * 1024 + c;
    float4 xv = *(const float4*)&X[t];
    float4 out;
    out.x = dsk * xv.x + s0;
    out.y = dsk * xv.y + s1;
    out.z = dsk * xv.z + s2;
    out.w = dsk * xv.w + s3;
    *(float4*)&Y[t] = out;
}

extern "C" void kernel_launch(void* const* d_in, const int* in_sizes, int n_in,
                              void* d_out, int out_size, void* d_ws, size_t ws_size,
                              hipStream_t stream) {
    const float* X    = (const float*)d_in[0];
    const float* A    = (const float*)d_in[1];
    const float* Bv   = (const float*)d_in[2];
    const float* Cv   = (const float*)d_in[3];
    const float* Dp   = (const float*)d_in[4];
    const float* logd = (const float*)d_in[5];
    float* ws = (float*)d_ws;

    float* S0 = ws;                 // e, squaring ping-pong
    float* S1 = ws + (size_t)NN2;   // e2
    float* S2 = ws + 2*(size_t)NN2; // e^2+e^4
    float* S3 = ws + 3*(size_t)NN2; // e+e^2
    float* S4 = ws + 4*(size_t)NN2; // D1, squaring ping-pong
    float* MP = ws + 5*(size_t)NN2; // mm partials (2 x NN2); also conv partials + chain partials
    float* CP = MP + (size_t)NN2;   // chain partials (inside mm partial 1, disjoint lifetime)
    float* Q  = ws + 7*(size_t)NN2;         // 128 x 1024
    float* P  = Q + 128*(size_t)N1;         // 128 x 1024
    float* Kc = P + 128*(size_t)N1;         // 16384
    float* Y  = (float*)d_out;

    dim3 mmg(16, 16, 2);

#define MM(Ain, Bin, Cout, al, be) \
    k_mmk<<<mmg, 256, 0, stream>>>(Ain, Bin, MP); \
    k_mmred<<<1024, 256, 0, stream>>>(MP, Ain, Cout, al, be);

    k_scale<<<4096, 256, 0, stream>>>(A, logd, S0);      // e = (d/2)A
    MM(S0, S0, S1, 1.f, 0.f);                            // e^2
    MM(S1, S1, S2, 1.f, 1.f);                            // e^2+e^4
    k_add<<<4096, 256, 0, stream>>>(S0, S1, S3);         // e+e^2
    MM(S3, S2, S4, 2.f, 2.f);                            // D1 = 2e(I+e)(I+e^2+e^4)

    // init: Q[0] = d*(B + 0.5*D1@B) via chainQ partials; P[0] = C
    k_chainQ1<<<dim3(16, 16, 1), 256, 0, stream>>>(S4, Bv, CP, 16, 64);
    k_initR<<<4, 256, 0, stream>>>(Bv, Cv, logd, CP, Q, P);

    // Q doubling with D_{2^k}; squaring D -> D^2 + 2D
    float* cur = S4;
    float* nxt = S0;
    for (int k = 0; k < 7; ++k) {
        int w = 1 << k;
        int kc = (w == 1) ? 16 : (w <= 4 ? 8 : 4);
        k_chainQ1<<<dim3(16, kc, w), 256, 0, stream>>>(cur, Q, CP, kc, N1 / kc);
        k_chainR<<<dim3(4, w), 256, 0, stream>>>(Q, CP, w, kc);
        MM(cur, cur, nxt, 1.f, 2.f);
        float* tsw = cur; cur = nxt; nxt = tsw;
    }
    // cur = D_128: P doubling (row form)
    for (int k = 0; k < 7; ++k) {
        int w = 1 << k;
        int kc = (w == 1) ? 16 : (w <= 4 ? 8 : 4);
        k_chainP1<<<dim3(16, kc, w), 256, 0, stream>>>(cur, P, CP, kc, N1 / kc);
        k_chainR<<<dim3(4, w), 256, 0, stream>>>(P, CP, w, kc);
        if (k < 6) {
            MM(cur, cur, nxt, 1.f, 2.f);
            float* tsw = cur; cur = nxt; nxt = tsw;
        }
    }
    k_kdot<<<4096, 256, 0, stream>>>(P, Q, Kc);
    k_conv1<<<544, 256, 0, stream>>>(X, Kc, MP);
    k_conv2<<<16, 256, 0, stream>>>(X, MP, Dp, Y);
#undef MM
}

// Round 4
// 795.732 us; speedup vs baseline: 1.6486x; 1.1159x over previous
//
#include <hip/hip_runtime.h>
#include <math.h>

#define N1 1024
#define NN2 (N1*N1)
#define LL 16384

// ---------------- elementwise ----------------
__global__ __launch_bounds__(256) void k_scale(const float* __restrict__ A,
                                               const float* __restrict__ logd,
                                               float* __restrict__ e) {
    int i = blockIdx.x * 256 + threadIdx.x;
    float d = expf(logd[0]);
    e[i] = 0.5f * d * A[i];
}

__global__ __launch_bounds__(256) void k_add(const float* __restrict__ a,
                                             const float* __restrict__ b,
                                             float* __restrict__ o) {
    int i = blockIdx.x * 256 + threadIdx.x;
    o[i] = a[i] + b[i];
}

// ---------------- chain-partial device code (mode 0 = Q rows, 1 = P cols) --------
// cb in [0, 16*kc*w): i = cb>>(4+lkc), ky = (cb>>4)&(kc-1), nx = cb&15
// kc==1: full dot, direct write V[w+i] = V[i] + M@V[i] (or P[i]@M)
// kc>1 : partial dot over mlen=N1/kc, write CP[(i*kc+ky)*N1 + n]
__device__ __forceinline__ void chain_part(const float* __restrict__ M,
                                           float* __restrict__ V,
                                           float* __restrict__ CP,
                                           int w, int lkc, int mode, int cb,
                                           float* sV, float (*red)[64]) {
    int kc = 1 << lkc;
    int i = cb >> (4 + lkc);
    int ky = (cb >> 4) & (kc - 1);
    int nx = cb & 15;
    int mlen = N1 >> lkc;
    int m0 = ky * mlen, n0 = nx * 64;
    int t = threadIdx.x;
    const float* Vi = V + (size_t)i * N1 + m0;
    if (t * 4 < mlen) *(float4*)&sV[t * 4] = *(const float4*)&Vi[t * 4];
    __syncthreads();
    int wave = t >> 6, lane = t & 63;
    if (mode == 0) {
        for (int rr = 0; rr < 16; ++rr) {
            int n = n0 + wave * 16 + rr;
            const float* Mr = M + (size_t)n * N1 + m0;
            float acc = 0.f;
            for (int m = lane * 4; m < mlen; m += 256) {
                float4 a = *(const float4*)&Mr[m];
                float4 v = *(const float4*)&sV[m];
                acc += a.x * v.x + a.y * v.y + a.z * v.z + a.w * v.w;
            }
#pragma unroll
            for (int off = 32; off > 0; off >>= 1) acc += __shfl_down(acc, off, 64);
            if (lane == 0) {
                if (kc == 1) V[(size_t)(w + i) * N1 + n] = sV[n] + acc;
                else CP[((size_t)i * kc + ky) * N1 + n] = acc;
            }
        }
    } else {
        int n = n0 + lane;
        int msub = mlen >> 2;
        int mb = wave * msub;
        float acc = 0.f;
#pragma unroll 8
        for (int m = 0; m < msub; ++m)
            acc += sV[mb + m] * M[(size_t)(m0 + mb + m) * N1 + n];
        red[wave][lane] = acc;
        __syncthreads();
        if (t < 64) {
            float s = red[0][t] + red[1][t] + red[2][t] + red[3][t];
            if (kc == 1) V[(size_t)(w + i) * N1 + n0 + t] = sV[n0 + t] + s;
            else CP[((size_t)i * kc + ky) * N1 + n0 + t] = s;
        }
    }
}

// ---------------- fused dispatch: [chain blocks | 512 SGEMM split-K partial blocks] --
// GEMM: part[z] = Ain[:, z*512:(z+1)*512] @ Bin[z*512:..., :], 64x64 tile, BK=32,
// double-buffered LDS, 4x4/thread.
__global__ __launch_bounds__(256) void k_fused(const float* __restrict__ Ain,
                                               const float* __restrict__ Bin,
                                               float* __restrict__ part,
                                               float* __restrict__ V,
                                               float* __restrict__ CP,
                                               int w, int lkc, int nchain, int mode) {
    __shared__ float As[2][32][68];
    __shared__ float Bs[2][32][68];
    __shared__ float sV[N1];
    __shared__ float red[4][64];
    int b = blockIdx.x;
    if (b < nchain) {
        chain_part(Ain, V, CP, w, lkc, mode, b, sV, red);
        return;
    }
    int g = b - nchain;
    int t = threadIdx.x;
    int z = g >> 8, ty = (g >> 4) & 15, tx = g & 15;
    int m0 = ty * 64, n0 = tx * 64, kz = z * 512;
    int tm = (t & 15) * 4, tn = (t >> 4) * 4;
    int lmA = t >> 2, lkA = (t & 3) * 8;
    int kbB = t >> 3, nbB = (t & 7) * 8;
    const float* Ap = Ain + (size_t)(m0 + lmA) * N1 + kz + lkA;
    const float* Bp = Bin + (size_t)(kz + kbB) * N1 + n0 + nbB;

    float4 pa0 = *(const float4*)(Ap);
    float4 pa1 = *(const float4*)(Ap + 4);
    float4 pb0 = *(const float4*)(Bp);
    float4 pb1 = *(const float4*)(Bp + 4);
    As[0][lkA + 0][lmA] = pa0.x; As[0][lkA + 1][lmA] = pa0.y;
    As[0][lkA + 2][lmA] = pa0.z; As[0][lkA + 3][lmA] = pa0.w;
    As[0][lkA + 4][lmA] = pa1.x; As[0][lkA + 5][lmA] = pa1.y;
    As[0][lkA + 6][lmA] = pa1.z; As[0][lkA + 7][lmA] = pa1.w;
    *(float4*)&Bs[0][kbB][nbB]     = pb0;
    *(float4*)&Bs[0][kbB][nbB + 4] = pb1;
    __syncthreads();

    float acc[4][4];
#pragma unroll
    for (int i = 0; i < 4; ++i)
#pragma unroll
        for (int j = 0; j < 4; ++j) acc[i][j] = 0.f;

    for (int tt = 0; tt < 16; ++tt) {
        int cur = tt & 1;
        float4 na0, na1, nb0, nb1;
        if (tt < 15) {
            int k0 = (tt + 1) * 32;
            na0 = *(const float4*)(Ap + k0);
            na1 = *(const float4*)(Ap + k0 + 4);
            nb0 = *(const float4*)(Bp + (size_t)k0 * N1);
            nb1 = *(const float4*)(Bp + (size_t)k0 * N1 + 4);
        }
#pragma unroll
        for (int k = 0; k < 32; ++k) {
            float4 a = *(float4*)&As[cur][k][tm];
            float4 bb = *(float4*)&Bs[cur][k][tn];
            acc[0][0] += a.x * bb.x; acc[0][1] += a.x * bb.y; acc[0][2] += a.x * bb.z; acc[0][3] += a.x * bb.w;
            acc[1][0] += a.y * bb.x; acc[1][1] += a.y * bb.y; acc[1][2] += a.y * bb.z; acc[1][3] += a.y * bb.w;
            acc[2][0] += a.z * bb.x; acc[2][1] += a.z * bb.y; acc[2][2] += a.z * bb.z; acc[2][3] += a.z * bb.w;
            acc[3][0] += a.w * bb.x; acc[3][1] += a.w * bb.y; acc[3][2] += a.w * bb.z; acc[3][3] += a.w * bb.w;
        }
        if (tt < 15) {
            int nxt = cur ^ 1;
            As[nxt][lkA + 0][lmA] = na0.x; As[nxt][lkA + 1][lmA] = na0.y;
            As[nxt][lkA + 2][lmA] = na0.z; As[nxt][lkA + 3][lmA] = na0.w;
            As[nxt][lkA + 4][lmA] = na1.x; As[nxt][lkA + 5][lmA] = na1.y;
            As[nxt][lkA + 6][lmA] = na1.z; As[nxt][lkA + 7][lmA] = na1.w;
            *(float4*)&Bs[nxt][kbB][nbB]     = nb0;
            *(float4*)&Bs[nxt][kbB][nbB + 4] = nb1;
            __syncthreads();
        }
    }
    float* Po = part + (size_t)z * NN2;
#pragma unroll
    for (int i = 0; i < 4; ++i) {
        float4 o = {acc[i][0], acc[i][1], acc[i][2], acc[i][3]};
        *(float4*)&Po[(size_t)(m0 + tm + i) * N1 + n0 + tn] = o;
    }
}

// ---------------- chain-partial-only dispatch (init Q0, final P step) -------------
__global__ __launch_bounds__(256) void k_cpart(const float* __restrict__ M,
                                               float* __restrict__ V,
                                               float* __restrict__ CP,
                                               int w, int lkc, int mode) {
    __shared__ float sV[N1];
    __shared__ float red[4][64];
    chain_part(M, V, CP, w, lkc, mode, blockIdx.x, sV, red);
}

// ---------------- fused reduce: [1024 mmred blocks | 4w chainR blocks] ------------
// mmred: Cout = alpha*(p0+p1) + beta*Ain ; chainR: V[w+i] = V[i] + sum_c CP[i][c]
__global__ __launch_bounds__(256) void k_redu(const float* __restrict__ part,
                                              const float* __restrict__ Aadd,
                                              float* __restrict__ C,
                                              float alpha, float beta,
                                              float* __restrict__ V,
                                              const float* __restrict__ CP,
                                              int w, int kc) {
    int b = blockIdx.x, t = threadIdx.x;
    if (b < 1024) {
        int i = (b * 256 + t) * 4;
        float4 p0 = *(const float4*)&part[i];
        float4 p1 = *(const float4*)&part[NN2 + i];
        float4 av = *(const float4*)&Aadd[i];
        float4 o;
        o.x = alpha * (p0.x + p1.x) + beta * av.x;
        o.y = alpha * (p0.y + p1.y) + beta * av.y;
        o.z = alpha * (p0.z + p1.z) + beta * av.z;
        o.w = alpha * (p0.w + p1.w) + beta * av.w;
        *(float4*)&C[i] = o;
    } else {
        int rb = b - 1024;
        int i = rb >> 2;
        int n = (rb & 3) * 256 + t;
        const float* pp = CP + (size_t)i * kc * N1 + n;
        float s = 0.f;
        for (int c = 0; c < kc; ++c) s += pp[(size_t)c * N1];
        V[(size_t)(w + i) * N1 + n] = V[(size_t)i * N1 + n] + s;
    }
}

// ---------------- init reduce: Q[0] = d*(B + 0.5*D1@B); P[0] = C ----------------
__global__ __launch_bounds__(256) void k_initR(const float* __restrict__ Bv,
                                               const float* __restrict__ Cv,
                                               const float* __restrict__ logd,
                                               const float* __restrict__ part,
                                               float* __restrict__ Q,
                                               float* __restrict__ P) {
    int n = blockIdx.x * 256 + threadIdx.x;
    float s = 0.f;
    for (int c = 0; c < 16; ++c) s += part[(size_t)c * N1 + n];
    float d = expf(logd[0]);
    Q[n] = d * (Bv[n] + 0.5f * s);
    P[n] = Cv[n];
}

// ---------------- K[a*128+b] = dot(P[a], Q[b]) ----------------
__global__ __launch_bounds__(256) void k_kdot(const float* __restrict__ P,
                                              const float* __restrict__ Q,
                                              float* __restrict__ K) {
    int t = threadIdx.x;
    int wid = blockIdx.x * 4 + (t >> 6), lane = t & 63;
    int a = wid >> 7, b = wid & 127;
    const float* Pr = P + (size_t)a * N1;
    const float* Qr = Q + (size_t)b * N1;
    float acc = 0.f;
#pragma unroll
    for (int jj = 0; jj < 4; ++jj) {
        int m = jj * 256 + lane * 4;
        float4 p = *(const float4*)&Pr[m];
        float4 q = *(const float4*)&Qr[m];
        acc += p.x * q.x + p.y * q.y + p.z * q.z + p.w * q.w;
    }
#pragma unroll
    for (int off = 32; off > 0; off >>= 1) acc += __shfl_down(acc, off, 64);
    if (lane == 0) K[wid] = acc;
}

// ---------------- conv phase 1 ----------------
__global__ __launch_bounds__(256) void k_conv1(const float* __restrict__ X,
                                               const float* __restrict__ K,
                                               float* __restrict__ part) {
    __shared__ __align__(16) float ks[1280];
    __shared__ __align__(16) float xs[256];
    int bx = blockIdx.x, tt = threadIdx.x;
    int o = 0;
    while (bx >= 2 * (o + 1) * (o + 1) + 2 * (o + 1)) ++o;
    int jt = bx - (2 * o * o + 2 * o);
    int T0 = o * 1024, J0 = jt * 256;
    int mb = T0 - J0 - 255;
    for (int ii = tt; ii < 1280; ii += 256) {
        int m = mb + ii;
        ks[ii] = (m >= 0 && m < LL) ? K[m] : 0.f;
    }
    xs[tt] = X[J0 + tt];
    __syncthreads();

    float acc0 = 0.f, acc1 = 0.f, acc2 = 0.f, acc3 = 0.f;
    int base0 = 4 * tt + 252;
#pragma unroll 4
    for (int jj = 0; jj < 256; jj += 4) {
        float4 xv  = *(const float4*)&xs[jj];
        float4 kv0 = *(const float4*)&ks[base0 - jj];
        float4 kv1 = *(const float4*)&ks[base0 - jj + 4];
        float kk0 = kv0.x, kk1 = kv0.y, kk2 = kv0.z, kk3 = kv0.w;
        float kk4 = kv1.x, kk5 = kv1.y, kk6 = kv1.z;
        acc0 += kk3 * xv.x + kk2 * xv.y + kk1 * xv.z + kk0 * xv.w;
        acc1 += kk4 * xv.x + kk3 * xv.y + kk2 * xv.z + kk1 * xv.w;
        acc2 += kk5 * xv.x + kk4 * xv.y + kk3 * xv.z + kk2 * xv.w;
        acc3 += kk6 * xv.x + kk5 * xv.y + kk4 * xv.z + kk3 * xv.w;
    }
    float4 out = {acc0, acc1, acc2, acc3};
    *(float4*)&part[((size_t)(o * 64 + jt)) * 1024 + 4 * tt] = out;
}

// ---------------- conv phase 2 ----------------
__global__ __launch_bounds__(256) void k_conv2(const float* __restrict__ X,
                                               const float* __restrict__ part,
                                               const float* __restrict__ Dp,
                                               float* __restrict__ Y) {
    int o = blockIdx.x, tt = threadIdx.x;
    int c = 4 * tt;
    float s0 = 0.f, s1 = 0.f, s2 = 0.f, s3 = 0.f;
    int cnt = 4 * o + 4;
    for (int jt = 0; jt < cnt; ++jt) {
        float4 p = *(const float4*)&part[((size_t)(o * 64 + jt)) * 1024 + c];
        s0 += p.x; s1 += p.y; s2 += p.z; s3 += p.w;
    }
    float dsk = Dp[0];
    int t = o * 1024 + c;
    float4 xv = *(const float4*)&X[t];
    float4 out;
    out.x = dsk * xv.x + s0;
    out.y = dsk * xv.y + s1;
    out.z = dsk * xv.z + s2;
    out.w = dsk * xv.w + s3;
    *(float4*)&Y[t] = out;
}

extern "C" void kernel_launch(void* const* d_in, const int* in_sizes, int n_in,
                              void* d_out, int out_size, void* d_ws, size_t ws_size,
                              hipStream_t stream) {
    const float* X    = (const float*)d_in[0];
    const float* A    = (const float*)d_in[1];
    const float* Bv   = (const float*)d_in[2];
    const float* Cv   = (const float*)d_in[3];
    const float* Dp   = (const float*)d_in[4];
    const float* logd = (const float*)d_in[5];
    float* ws = (float*)d_ws;

    float* S0 = ws;                 // e, squaring ping-pong
    float* S1 = ws + (size_t)NN2;   // e2
    float* S2 = ws + 2*(size_t)NN2; // e^2+e^4
    float* S3 = ws + 3*(size_t)NN2; // e+e^2
    float* S4 = ws + 4*(size_t)NN2; // D1, squaring ping-pong
    float* MP = ws + 5*(size_t)NN2; // mm partials (2 x NN2); also conv partials
    float* CP = ws + 7*(size_t)NN2; // chain partials (<=64 KB)
    float* Q  = CP + 64*(size_t)N1;         // 128 x 1024
    float* P  = Q + 128*(size_t)N1;         // 128 x 1024
    float* Kc = P + 128*(size_t)N1;         // 16384
    float* Y  = (float*)d_out;

    k_scale<<<4096, 256, 0, stream>>>(A, logd, S0);      // e = (d/2)A
    // build D1 = 2e(I+e)(I+e^2+e^4): 3 GEMM pairs, no chain fused
    k_fused<<<512, 256, 0, stream>>>(S0, S0, MP, nullptr, nullptr, 0, 0, 0, 0);
    k_redu<<<1024, 256, 0, stream>>>(MP, S0, S1, 1.f, 0.f, nullptr, nullptr, 0, 0);
    k_fused<<<512, 256, 0, stream>>>(S1, S1, MP, nullptr, nullptr, 0, 0, 0, 0);
    k_redu<<<1024, 256, 0, stream>>>(MP, S1, S2, 1.f, 1.f, nullptr, nullptr, 0, 0);
    k_add<<<4096, 256, 0, stream>>>(S0, S1, S3);
    k_fused<<<512, 256, 0, stream>>>(S3, S2, MP, nullptr, nullptr, 0, 0, 0, 0);
    k_redu<<<1024, 256, 0, stream>>>(MP, S3, S4, 2.f, 2.f, nullptr, nullptr, 0, 0);

    // init: Q[0] = d*(B + 0.5*D1@B); P[0] = C
    k_cpart<<<256, 256, 0, stream>>>(S4, (float*)Bv, CP, 1, 4, 0);
    k_initR<<<4, 256, 0, stream>>>(Bv, Cv, logd, CP, Q, P);

    float* cur = S4;
    float* nxt = S0;
    // Q loop: chain step w=2^k with D_{2^k}, fused with squaring -> D_{2^{k+1}}
    for (int k = 0; k < 7; ++k) {
        int w = 1 << k;
        int lkc = (w < 16) ? (4 - k) : 0;
        int kc = 1 << lkc;
        int nchain = 16 * kc * w;
        int nR = (kc > 1) ? 4 * w : 0;
        k_fused<<<nchain + 512, 256, 0, stream>>>(cur, cur, MP, Q, CP, w, lkc, nchain, 0);
        k_redu<<<1024 + nR, 256, 0, stream>>>(MP, cur, nxt, 1.f, 2.f, Q, CP, w, kc);
        float* tsw = cur; cur = nxt; nxt = tsw;
    }
    // P loop: k=0..5 fused with squarings (D_128..D_4096 -> up to D_8192)
    for (int k = 0; k < 6; ++k) {
        int w = 1 << k;
        int lkc = (w < 16) ? (4 - k) : 0;
        int kc = 1 << lkc;
        int nchain = 16 * kc * w;
        int nR = (kc > 1) ? 4 * w : 0;
        k_fused<<<nchain + 512, 256, 0, stream>>>(cur, cur, MP, P, CP, w, lkc, nchain, 1);
        k_redu<<<1024 + nR, 256, 0, stream>>>(MP, cur, nxt, 1.f, 2.f, P, CP, w, kc);
        float* tsw = cur; cur = nxt; nxt = tsw;
    }
    // final P step: w=64 with D_8192, direct write
    k_cpart<<<1024, 256, 0, stream>>>(cur, P, CP, 64, 0, 1);

    k_kdot<<<4096, 256, 0, stream>>>(P, Q, Kc);
    k_conv1<<<544, 256, 0, stream>>>(X, Kc, MP);
    k_conv2<<<16, 256, 0, stream>>>(X, MP, Dp, Y);
}